// Round 4
// baseline (1216.953 us; speedup 1.0000x reference)
//
#include <hip/hip_runtime.h>

#define B_ 64
#define T_ 256
#define DIN_ 1024
#define DOUT_ 1024
#define KC 32     // k-chunk staged in LDS
#define NO 16     // outputs (o) per wave

// -----------------------------------------------------------------------------
// Prep: W64[o][k] = (double)W[o][k]   (1M elems; ~5 us)
// -----------------------------------------------------------------------------
__global__ __launch_bounds__(256) void snn_prep(const float* __restrict__ W,
                                                double* __restrict__ W64)
{
    const int i = blockIdx.x * 256 + threadIdx.x;
    const float4 v = ((const float4*)W)[i];
    double2* d = (double2*)(W64 + 4 * (size_t)i);
    d[0] = make_double2((double)v.x, (double)v.y);
    d[1] = make_double2((double)v.z, (double)v.w);
}

// -----------------------------------------------------------------------------
// GEMM: pre[t][o][b] = sum_k x[b][t][k] * W[o][k]     (bias added in scan)
// lane = b (64 per wave); each wave owns NO=16 o's. W operand is wave-uniform
// -> scalar s_load (SMEM pipe) -> v_fma_f64 with one SGPR-pair source.
// Only the A slice x[.,t0,k-chunk] flows through LDS: 2 ds_read_b64 / 32 FMA.
// -----------------------------------------------------------------------------
__global__ __launch_bounds__(256) void snn_gemm(
    const float* __restrict__ x, const double* __restrict__ W64,
    double* __restrict__ pre)
{
    __shared__ double Ak[2][KC][64];   // 32 KB, double-buffered

    const int t0  = blockIdx.x & 255;
    const int og0 = blockIdx.x >> 8;        // 0..15
    const int tid = threadIdx.x;
    const int lane = tid & 63;
    // wave-uniform o-base, forced into an SGPR so W loads scalarize
    const int obase = __builtin_amdgcn_readfirstlane(og0 * 64 + (tid >> 6) * NO);
    const double* Wp = W64 + (size_t)obase * DIN_;

    double acc[NO];
#pragma unroll
    for (int j = 0; j < NO; ++j) acc[j] = 0.0;

    // staging: thread (bb = tid>>2) loads 8 consecutive k (two float4) per chunk
    const int bb  = tid >> 2;
    const int kq8 = (tid & 3) * 8;
    const float* xp = x + (size_t)bb * (T_ * DIN_) + (size_t)t0 * DIN_ + kq8;

    float4 f0 = *(const float4*)(xp);
    float4 f1 = *(const float4*)(xp + 4);

    for (int kc = 0; kc < DIN_ / KC; ++kc) {
        const int buf = kc & 1;
        Ak[buf][kq8 + 0][bb] = (double)f0.x;
        Ak[buf][kq8 + 1][bb] = (double)f0.y;
        Ak[buf][kq8 + 2][bb] = (double)f0.z;
        Ak[buf][kq8 + 3][bb] = (double)f0.w;
        Ak[buf][kq8 + 4][bb] = (double)f1.x;
        Ak[buf][kq8 + 5][bb] = (double)f1.y;
        Ak[buf][kq8 + 6][bb] = (double)f1.z;
        Ak[buf][kq8 + 7][bb] = (double)f1.w;
        __syncthreads();
        if (kc + 1 < DIN_ / KC) {       // prefetch next chunk (used next iter)
            f0 = *(const float4*)(xp + (kc + 1) * KC);
            f1 = *(const float4*)(xp + (kc + 1) * KC + 4);
        }
        const int kbase = kc * KC;
#pragma unroll
        for (int k2 = 0; k2 < KC; k2 += 2) {
            const double a0 = Ak[buf][k2 + 0][lane];   // ds_read_b64, 2-way=free
            const double a1 = Ak[buf][k2 + 1][lane];
            const double* wrow = Wp + kbase + k2;      // uniform -> s_load_dwordx4
#pragma unroll
            for (int j = 0; j < NO; ++j) {
                acc[j] = __builtin_fma(a0, wrow[(size_t)j * DIN_ + 0], acc[j]);
                acc[j] = __builtin_fma(a1, wrow[(size_t)j * DIN_ + 1], acc[j]);
            }
        }
    }

    // stores: 64 lanes x 8 B contiguous (512 B) per j
    double* dst = pre + ((size_t)t0 * DOUT_ + obase) * 64 + lane;
#pragma unroll
    for (int j = 0; j < NO; ++j) dst[(size_t)j * 64] = acc[j];
}

// -----------------------------------------------------------------------------
// Scan: one wave per o, lane = b. Bias folded into the load (same fp64 ops as
// adding it in the GEMM epilogue). Batch mean via ballot+popcount.
// -----------------------------------------------------------------------------
__global__ __launch_bounds__(256) void snn_scan(
    const double* __restrict__ pre, const float* __restrict__ bias,
    const float* __restrict__ thr_in,
    float* __restrict__ spT, float* __restrict__ outD)
{
    const int wid  = (blockIdx.x * blockDim.x + threadIdx.x) >> 6;
    const int lane = threadIdx.x & 63;
    if (wid >= DOUT_) return;
    const int o = wid;

    double mem = 0.0;
    double thr = (double)thr_in[o];
    const double biasd = (double)bias[o];
    const double* p = pre + (size_t)o * 64 + lane;

    for (int t = 0; t < T_; t += 4) {
        double pv[4];
#pragma unroll
        for (int j = 0; j < 4; ++j)
            pv[j] = p[(size_t)(t + j) * (DOUT_ * 64)] + biasd;
#pragma unroll
        for (int j = 0; j < 4; ++j) {
            mem += pv[j];
            const bool s = (mem >= thr);
            const unsigned long long msk = __ballot(s);
            const int cnt = __popcll(msk);
            thr += 0.05 * ((double)cnt * (1.0 / 64.0) - 0.5);
            const float sf = s ? 1.0f : 0.0f;
            if (spT) {
                spT[(size_t)(t + j) * (DOUT_ * 64) + (size_t)o * 64 + lane] = sf;
            } else {
                outD[(size_t)lane * (T_ * DOUT_) + (size_t)(t + j) * DOUT_ + o] = sf;
            }
            mem = s ? 0.0 : mem;
        }
    }
}

// -----------------------------------------------------------------------------
// Transpose: spT [(t*O+o)][64 b] -> out [64 b][(t*O+o)]
// -----------------------------------------------------------------------------
__global__ __launch_bounds__(256) void snn_transpose(
    const float* __restrict__ spT, float* __restrict__ out)
{
    __shared__ float tile[64][65];
    const int R0   = blockIdx.x * 64;
    const int lane = threadIdx.x & 63;
    const int grp  = threadIdx.x >> 6;
#pragma unroll
    for (int rr = grp; rr < 64; rr += 4)
        tile[rr][lane] = spT[(size_t)(R0 + rr) * 64 + lane];
    __syncthreads();
#pragma unroll
    for (int bq = grp; bq < 64; bq += 4)
        out[(size_t)bq * (T_ * DOUT_) + R0 + lane] = tile[lane][bq];
}

extern "C" void kernel_launch(void* const* d_in, const int* in_sizes, int n_in,
                              void* d_out, int out_size, void* d_ws, size_t ws_size,
                              hipStream_t stream) {
    const float* x    = (const float*)d_in[0];   // [64][256][1024]
    const float* W    = (const float*)d_in[1];   // [1024][1024]
    const float* bias = (const float*)d_in[2];   // [1024]
    const float* thr  = (const float*)d_in[3];   // [1024]
    float* out = (float*)d_out;                  // [64][256][1024]

    double* pre = (double*)d_ws;
    const size_t preBytes = (size_t)T_ * DOUT_ * B_ * sizeof(double);  // 128 MiB
    const size_t spBytes  = (size_t)T_ * DOUT_ * B_ * sizeof(float);   //  64 MiB
    const bool two_stage = (ws_size >= preBytes + spBytes);
    // W64 (8 MiB) aliases the spT region: GEMM finishes reading it before the
    // scan (stream-ordered) writes spT over it.
    double* W64 = (double*)((char*)d_ws + preBytes);
    float*  spT = two_stage ? (float*)((char*)d_ws + preBytes) : nullptr;

    snn_prep<<<1024, 256, 0, stream>>>(W, W64);
    snn_gemm<<<4096, 256, 0, stream>>>(x, W64, pre);
    snn_scan<<<256, 256, 0, stream>>>(pre, bias, thr, spT, two_stage ? nullptr : out);
    if (two_stage)
        snn_transpose<<<4096, 256, 0, stream>>>(spT, out);
}

// Round 5
// 909.411 us; speedup vs baseline: 1.3382x; 1.3382x over previous
//
#include <hip/hip_runtime.h>

#define B_ 64
#define T_ 256
#define DIN_ 1024
#define DOUT_ 1024

// -----------------------------------------------------------------------------
// GEMM: pre[t][o][b] (fp64) = sum_k x[b][t][k] * W[o][k] + bias[o]
// Block = (t0 fixed) x (o-tile 128), all 64 b. Thread (to,tb):
//   b = tb*4+i (i<4),  o_local = j4*64 + to*4 + p4 (j = j4*4+p4 < 8).
// LDS tiles are fp32 (half traffic); fragments read as b128 only:
//   a: 1x ds_read_b128 (4 floats), b: 2x ds_read_b128 (8 floats) per k.
// Convert to fp64 in registers; accumulate fp64 sequentially over k.
// -----------------------------------------------------------------------------
__global__ __launch_bounds__(256) void snn_gemm(
    const float* __restrict__ x, const float* __restrict__ W,
    const float* __restrict__ bias, double* __restrict__ pre)
{
    __shared__ float smem[16 * 68 + 16 * 128];   // 12544 B
    float (*AsF)[68]  = (float(*)[68])smem;            // [k][b], row=272B (16B-aligned)
    float (*BsF)[128] = (float(*)[128])(smem + 16 * 68); // [k][o_local]

    const int t0 = blockIdx.x & 255;
    const int o0 = blockIdx.x >> 8;      // 0..7
    const int tid = threadIdx.x;
    const int to = tid & 15;
    const int tb = tid >> 4;

    double acc[4][8];
#pragma unroll
    for (int i = 0; i < 4; ++i)
#pragma unroll
        for (int j = 0; j < 8; ++j) acc[i][j] = 0.0;

    // staging: A = 64 rows(b) x 16 k (4 floats/thread); B = 128 rows(o) x 16 k (8 floats/thread)
    const int arow = tid >> 2;           // b
    const int ak   = (tid & 3) * 4;
    const int worow = tid >> 1;          // o_local
    const int wk    = (tid & 1) * 8;

    const float* xg = x + (size_t)(t0 + 256 * arow) * DIN_ + ak;
    const float* wg = W + (size_t)(o0 * 128 + worow) * DIN_ + wk;

    float4 av  = *(const float4*)(xg);
    float4 bv0 = *(const float4*)(wg);
    float4 bv1 = *(const float4*)(wg + 4);

    for (int kk = 0; kk < DIN_; kk += 16) {
        AsF[ak + 0][arow] = av.x;
        AsF[ak + 1][arow] = av.y;
        AsF[ak + 2][arow] = av.z;
        AsF[ak + 3][arow] = av.w;
        BsF[wk + 0][worow] = bv0.x;
        BsF[wk + 1][worow] = bv0.y;
        BsF[wk + 2][worow] = bv0.z;
        BsF[wk + 3][worow] = bv0.w;
        BsF[wk + 4][worow] = bv1.x;
        BsF[wk + 5][worow] = bv1.y;
        BsF[wk + 6][worow] = bv1.z;
        BsF[wk + 7][worow] = bv1.w;
        __syncthreads();

        if (kk + 16 < DIN_) {            // prefetch next tile
            av  = *(const float4*)(xg + kk + 16);
            bv0 = *(const float4*)(wg + kk + 16);
            bv1 = *(const float4*)(wg + kk + 20);
        }

#pragma unroll
        for (int k = 0; k < 16; ++k) {
            const float4 af  = *(const float4*)&AsF[k][tb * 4];        // 2-way, free
            const float4 bf0 = *(const float4*)&BsF[k][to * 4];        // 2-way, free
            const float4 bf1 = *(const float4*)&BsF[k][64 + to * 4];
            double a[4], b[8];
            a[0] = (double)af.x;  a[1] = (double)af.y;
            a[2] = (double)af.z;  a[3] = (double)af.w;
            b[0] = (double)bf0.x; b[1] = (double)bf0.y;
            b[2] = (double)bf0.z; b[3] = (double)bf0.w;
            b[4] = (double)bf1.x; b[5] = (double)bf1.y;
            b[6] = (double)bf1.z; b[7] = (double)bf1.w;
#pragma unroll
            for (int i = 0; i < 4; ++i)
#pragma unroll
                for (int j = 0; j < 8; ++j)
                    acc[i][j] += a[i] * b[j];   // v_fma_f64
        }
        __syncthreads();
    }

    // epilogue: bias + LDS transpose to b-contiguous stores.
    double biasd[8];
#pragma unroll
    for (int j = 0; j < 8; ++j)
        biasd[j] = (double)bias[o0 * 128 + (j >> 2) * 64 + to * 4 + (j & 3)];

    double (*trans)[67] = (double(*)[67])smem;   // 16 x 67 doubles = 8576 B, fits

    for (int c = 0; c < 8; ++c) {
        __syncthreads();
        // chunk c covers o_local in [c*16, c*16+16): j4 = c>>2, to in [(c&3)*4, +4)
        const int j4 = c >> 2;
        const int tlo = (c & 3) * 4;
        if (to >= tlo && to < tlo + 4) {
#pragma unroll
            for (int p4 = 0; p4 < 4; ++p4) {
                const int r = (to - tlo) * 4 + p4;
                const int j = j4 * 4 + p4;
#pragma unroll
                for (int i = 0; i < 4; ++i)
                    trans[r][tb * 4 + i] = acc[i][j] + biasd[j];
            }
        }
        __syncthreads();
#pragma unroll
        for (int q = 0; q < 4; ++q) {
            const int idx = tid + 256 * q;
            const int b  = idx & 63;
            const int oc = idx >> 6;       // 0..15
            pre[(size_t)(t0 * DOUT_ + o0 * 128 + c * 16 + oc) * 64 + b] = trans[oc][b];
        }
    }
}

// -----------------------------------------------------------------------------
// Scan: one wave per output unit o, lane = b. Batch-mean via ballot+popcount.
// -----------------------------------------------------------------------------
__global__ __launch_bounds__(256) void snn_scan(
    const double* __restrict__ pre, const float* __restrict__ thr_in,
    float* __restrict__ spT, float* __restrict__ outD)
{
    const int wid  = (blockIdx.x * blockDim.x + threadIdx.x) >> 6;
    const int lane = threadIdx.x & 63;
    if (wid >= DOUT_) return;
    const int o = wid;

    double mem = 0.0;
    double thr = (double)thr_in[o];
    const double* p = pre + (size_t)o * 64 + lane;

    for (int t = 0; t < T_; t += 4) {
        double pv[4];
#pragma unroll
        for (int j = 0; j < 4; ++j)
            pv[j] = p[(size_t)(t + j) * (DOUT_ * 64)];
#pragma unroll
        for (int j = 0; j < 4; ++j) {
            mem += pv[j];
            const bool s = (mem >= thr);
            const unsigned long long msk = __ballot(s);
            const int cnt = __popcll(msk);
            thr += 0.05 * ((double)cnt * (1.0 / 64.0) - 0.5);
            const float sf = s ? 1.0f : 0.0f;
            if (spT) {
                spT[(size_t)(t + j) * (DOUT_ * 64) + (size_t)o * 64 + lane] = sf;
            } else {
                outD[(size_t)lane * (T_ * DOUT_) + (size_t)(t + j) * DOUT_ + o] = sf;
            }
            mem = s ? 0.0 : mem;
        }
    }
}

// -----------------------------------------------------------------------------
// Transpose: spT [(t*O+o)][64 b] -> out [64 b][(t*O+o)]
// -----------------------------------------------------------------------------
__global__ __launch_bounds__(256) void snn_transpose(
    const float* __restrict__ spT, float* __restrict__ out)
{
    __shared__ float tile[64][65];
    const int R0   = blockIdx.x * 64;
    const int lane = threadIdx.x & 63;
    const int grp  = threadIdx.x >> 6;
#pragma unroll
    for (int rr = grp; rr < 64; rr += 4)
        tile[rr][lane] = spT[(size_t)(R0 + rr) * 64 + lane];
    __syncthreads();
#pragma unroll
    for (int bq = grp; bq < 64; bq += 4)
        out[(size_t)bq * (T_ * DOUT_) + R0 + lane] = tile[lane][bq];
}

extern "C" void kernel_launch(void* const* d_in, const int* in_sizes, int n_in,
                              void* d_out, int out_size, void* d_ws, size_t ws_size,
                              hipStream_t stream) {
    const float* x    = (const float*)d_in[0];   // [64][256][1024]
    const float* W    = (const float*)d_in[1];   // [1024][1024]
    const float* bias = (const float*)d_in[2];   // [1024]
    const float* thr  = (const float*)d_in[3];   // [1024]
    float* out = (float*)d_out;                  // [64][256][1024]

    double* pre = (double*)d_ws;
    const size_t preBytes = (size_t)T_ * DOUT_ * B_ * sizeof(double);  // 128 MiB
    const size_t spBytes  = (size_t)T_ * DOUT_ * B_ * sizeof(float);   //  64 MiB
    const bool two_stage = (ws_size >= preBytes + spBytes);
    float* spT = two_stage ? (float*)((char*)d_ws + preBytes) : nullptr;

    snn_gemm<<<2048, 256, 0, stream>>>(x, W, bias, pre);
    snn_scan<<<256, 256, 0, stream>>>(pre, thr, spT, two_stage ? nullptr : out);
    if (two_stage)
        snn_transpose<<<4096, 256, 0, stream>>>(spT, out);
}